// Round 6
// baseline (496.484 us; speedup 1.0000x reference)
//
#include <hip/hip_runtime.h>
#include <math.h>

#define BB 32
#define NN 1000
#define CC 128
#define FF 128
#define OO 64
#define CAP 128
#define NB 40

// exact replica of JAX's np.float32(1.0 - 0.8) = 0.20000000298023224f
#define RMC ((float)(1.0 - 0.8))

// ======== R16: CUT DISPATCHES (12->9) + PIPELINE agglin PHASE-1 ========
// Budget audit R5: all kernels sum to ~312 of 446.8us -> ~135us lives at the
// 11 dispatch boundaries (~12us each). k_pd = R2's verified pool+deg fusion
// (WITHOUT the serial score phase that sank spd); k_mfc = R2's verified
// fmax+fc fusion. agglin phase-1 gets a 1-deep row pipeline (prefetch next
// row's m/cnt/r while gathering current) - load scheduling only, bit-exact.

// ---- CSR build + stage-1 D/dg + fused pre-work (blocks with i==NN) ----
__global__ void k_csr(const float* __restrict__ A, const float* __restrict__ mask,
                      const int* __restrict__ Nn,
                      const float* __restrict__ p0, const float* __restrict__ p1,
                      const float* __restrict__ W0, const float* __restrict__ W1,
                      const float* __restrict__ W2,
                      short* __restrict__ idx, int* __restrict__ cnt,
                      float* __restrict__ D, float* __restrict__ dg,
                      float* __restrict__ m, float* __restrict__ gate,
                      int* __restrict__ ncur0, float* __restrict__ pn,
                      float* __restrict__ Wt){
  int blk = blockIdx.x, lane = threadIdx.x;   // grid 32032, block = 64 (one wave)
  int r8 = blk & 7, t = blk >> 3;             // t 0..4003
  int b = r8 + 8*(t/1001), i = t % 1001;      // XCD-spread decode
  if (i == NN){                            // ---- 32 pre-work blocks ----
    for (int j = lane; j < NN; j += 64){
      float v = mask[b*NN + j]; m[b*NN + j] = v; gate[b*NN + j] = v;
    }
    if (lane == 0) ncur0[b] = Nn[b];
    if (b == 0 && lane == 1){ float s=0.f; for(int c=0;c<FF;c++) s += p0[c]*p0[c]; pn[0] = sqrtf(s); }
    if (b == 1 && lane == 1){ float s=0.f; for(int c=0;c<FF;c++) s += p1[c]*p1[c]; pn[1] = sqrtf(s); }
    // Wt[s][c][f] = W[s][f][c]; 3*FF*CC = 49152 elems, 1536 per block
    for (int e = b*1536 + lane; e < (b+1)*1536; e += 64){
      int s = e / (FF*CC), rem = e % (FF*CC);
      int c = rem >> 7, f = rem & 127;
      const float* W = (s == 0) ? W0 : (s == 1) ? W1 : W2;
      Wt[(size_t)s*FF*CC + rem] = W[f*CC + c];
    }
    return;
  }
  if (mask[b*NN + i] == 0.f){              // A row is all-zero (A pre-masked)
    if (lane == 0){
      cnt[b*NN + i] = 0;
      D[b*NN + i]  = 1.0f / sqrtf(1.0f + 1e-5f);
      dg[b*NN + i] = 0.f;
    }
    return;
  }
  const float4* row = (const float4*)(A + ((size_t)b*NN + i)*NN);
  short* out = idx + ((size_t)b*NN + i)*CAP;
  int count = 0;
  for (int base = 0; base < 250; base += 64){               // 1000 = 250 float4
    int q = base + lane;
    float4 v;
    if (q < 250) v = row[q]; else { v.x=v.y=v.z=v.w=0.f; }
    int lc = (v.x!=0.f) + (v.y!=0.f) + (v.z!=0.f) + (v.w!=0.f);
    int pre = lc;
    #pragma unroll
    for (int off = 1; off < 64; off <<= 1){
      int t2 = __shfl_up(pre, off);
      if (lane >= off) pre += t2;
    }
    int tot = __shfl(pre, 63);
    pre -= lc;                                              // exclusive prefix
    int slot = count + pre;
    int j = q*4;
    if (v.x!=0.f && slot < CAP) out[slot++] = (short)j;
    if (v.y!=0.f && slot < CAP) out[slot++] = (short)(j+1);
    if (v.z!=0.f && slot < CAP) out[slot++] = (short)(j+2);
    if (v.w!=0.f && slot < CAP) out[slot++] = (short)(j+3);
    count += tot;
  }
  if (lane == 0){
    int cn = (count < CAP) ? count : CAP;
    cnt[b*NN + i] = cn;
    float Dv = 1.0f / sqrtf((float)cn + 1.0f + 1e-5f);
    D[b*NN + i]  = Dv;
    dg[b*NN + i] = Dv;                   // mask_i == 1 here
  }
}

// ---- FUSED: T-tile into LDS (phase 1, pipelined) + frozen GEMM (phase 2) ----
__global__ void k_agglin(const short* __restrict__ idx, const int* __restrict__ cnt,
                         const float* __restrict__ D, const float* __restrict__ dg,
                         const float* __restrict__ m, const float* __restrict__ gate,
                         const float* __restrict__ h,
                         const float* __restrict__ Wt,   // [cc][f] transposed
                         const float* __restrict__ bias, float* __restrict__ Hout){
  __shared__ float t[NB][CC];              // 20.5 KB (the old T staging buffer)
  __shared__ int   nb[4][CAP];             // per-wave gather scratch (2 KB)
  __shared__ float dn[4][CAP];             // (2 KB)
  int blk = blockIdx.x, tid = threadIdx.x; // grid 800, block = 256
  int r8 = blk & 7, tq = blk >> 3;         // tq 0..99
  int b = r8 + 8*(tq/25);
  int i0 = (tq % 25) * NB;
  int w = tid >> 6, lane = tid & 63;
  int g = lane >> 5, l32 = lane & 31;
  const float* hb = h + (size_t)b*NN*CC;
  int*   nbw = nb[w];
  float* dnw = dn[w];
  // ================= phase 1: aggregate 40 rows into t (1-deep pipeline) ====
  // prefetch row q=0 metadata + edge list (r[lane], r[lane+64] always in CAP)
  float pm; int pnn, pja, pjb;
  {
    int i = i0 + w;
    pm  = m[b*NN + i];
    pnn = cnt[b*NN + i];
    const short* rr = idx + ((size_t)b*NN + i)*CAP;
    pja = (int)rr[lane]; pjb = (int)rr[lane + 64];
  }
  for (int q = 0; q < 10; q++){            // wave w owns local rows w, w+4, ... w+36
    int lr = q*4 + w;
    int i  = i0 + lr;
    float mi = pm; int n = pnn; int ja = pja, jb = pjb;
    if (q < 9){                            // issue next row's independent loads
      int i2 = i0 + (q+1)*4 + w;
      pm  = m[b*NN + i2];
      pnn = cnt[b*NN + i2];
      const short* rr = idx + ((size_t)b*NN + i2)*CAP;
      pja = (int)rr[lane]; pjb = (int)rr[lane + 64];
    }
    if (mi == 0.f){                        // masked target: T row is zero
      if (g == 0){ float4 z = {0.f,0.f,0.f,0.f}; *(float4*)&t[lr][l32<<2] = z; }
      continue;                            // wave-uniform
    }
    float Di = D[b*NN + i];                // independent: issue before gather
    float gi = gate[b*NN + i];
    // --- wave-level order-preserving compaction (branch-free both halves) ---
    int j0 = (lane < n) ? ja : 0;
    float d0 = dg[b*NN + j0];
    bool k0 = (lane < n) && (d0 != 0.f);
    unsigned long long bal = __ballot(k0);
    int pre = __popcll(bal & ((1ull << lane) - 1ull));
    if (k0){ nbw[pre] = j0*CC; dnw[pre] = d0; }
    int nlive = __popcll(bal);
    {                                      // second half (no-op when n<=64)
      int e = lane + 64;
      int j1 = (e < n) ? jb : 0;
      float d1 = dg[b*NN + j1];
      bool k1 = (e < n) && (d1 != 0.f);
      unsigned long long bal1 = __ballot(k1);
      int pre1 = __popcll(bal1 & ((1ull << lane) - 1ull));
      if (k1){ nbw[nlive + pre1] = j1*CC; dnw[nlive + pre1] = d1; }
      nlive += __popcll(bal1);
    }
    int np = (nlive + 15) & ~15;           // pad to 16 (CAP=128 safe)
    if (lane < np - nlive){ nbw[nlive + lane] = 0; dnw[nlive + lane] = 0.f; }
    __builtin_amdgcn_wave_barrier();       // fence: LDS writes before reads
    // --- branch-free float4 gather, 8 loads/lane in flight ---
    float4 a0 = {0.f,0.f,0.f,0.f}, a1 = a0, a2 = a0, a3 = a0;
    for (int k = 0; k < np; k += 16){
      int e = k + g;
      float4 v0 = *(const float4*)(hb + nbw[e   ] + (l32<<2));
      float4 v1 = *(const float4*)(hb + nbw[e+ 2] + (l32<<2));
      float4 v2 = *(const float4*)(hb + nbw[e+ 4] + (l32<<2));
      float4 v3 = *(const float4*)(hb + nbw[e+ 6] + (l32<<2));
      float4 v4 = *(const float4*)(hb + nbw[e+ 8] + (l32<<2));
      float4 v5 = *(const float4*)(hb + nbw[e+10] + (l32<<2));
      float4 v6 = *(const float4*)(hb + nbw[e+12] + (l32<<2));
      float4 v7 = *(const float4*)(hb + nbw[e+14] + (l32<<2));
      float e0 = dnw[e], e1 = dnw[e+2], e2 = dnw[e+4], e3 = dnw[e+6];
      float e4 = dnw[e+8], e5 = dnw[e+10], e6 = dnw[e+12], e7 = dnw[e+14];
      a0.x += e0*v0.x; a0.y += e0*v0.y; a0.z += e0*v0.z; a0.w += e0*v0.w;
      a1.x += e1*v1.x; a1.y += e1*v1.y; a1.z += e1*v1.z; a1.w += e1*v1.w;
      a2.x += e2*v2.x; a2.y += e2*v2.y; a2.z += e2*v2.z; a2.w += e2*v2.w;
      a3.x += e3*v3.x; a3.y += e3*v3.y; a3.z += e3*v3.z; a3.w += e3*v3.w;
      a0.x += e4*v4.x; a0.y += e4*v4.y; a0.z += e4*v4.z; a0.w += e4*v4.w;
      a1.x += e5*v5.x; a1.y += e5*v5.y; a1.z += e5*v5.z; a1.w += e5*v5.w;
      a2.x += e6*v6.x; a2.y += e6*v6.y; a2.z += e6*v6.z; a2.w += e6*v6.w;
      a3.x += e7*v7.x; a3.y += e7*v7.y; a3.z += e7*v7.z; a3.w += e7*v7.w;
    }
    float4 Y;
    Y.x = (a0.x + a1.x) + (a2.x + a3.x);
    Y.y = (a0.y + a1.y) + (a2.y + a3.y);
    Y.z = (a0.z + a1.z) + (a2.z + a3.z);
    Y.w = (a0.w + a1.w) + (a2.w + a3.w);
    Y.x += __shfl_xor(Y.x, 32);            // combine the two 32-lane groups
    Y.y += __shfl_xor(Y.y, 32);
    Y.z += __shfl_xor(Y.z, 32);
    Y.w += __shfl_xor(Y.w, 32);
    if (g == 0){
      float4 hv = *(const float4*)(hb + (size_t)i*CC + (l32<<2));
      float4 o;
      o.x = Di*Y.x + Di*Di*(gi*hv.x);
      o.y = Di*Y.y + Di*Di*(gi*hv.y);
      o.z = Di*Y.z + Di*Di*(gi*hv.z);
      o.w = Di*Y.w + Di*Di*(gi*hv.w);
      *(float4*)&t[lr][l32<<2] = o;
    }
  }
  __syncthreads();
  // ================= phase 2: FROZEN R3 GEMM body (verbatim) =================
  int fg = tid & 31;                       // 4 consecutive f per thread
  int nr = tid >> 5;                       // 0..7 node-row
  float acc[5][4];
  float4 bi = ((const float4*)bias)[fg];
  #pragma unroll
  for (int n5 = 0; n5 < 5; n5++){
    acc[n5][0]=bi.x; acc[n5][1]=bi.y; acc[n5][2]=bi.z; acc[n5][3]=bi.w;
  }
  for (int c4 = 0; c4 < 32; c4++){
    float4 tv[5];
    #pragma unroll
    for (int n5 = 0; n5 < 5; n5++)
      tv[n5] = *((const float4*)&t[nr + n5*8][c4*4]);
    #pragma unroll
    for (int k = 0; k < 4; k++){
      float4 wv = ((const float4*)Wt)[(size_t)(c4*4 + k)*32 + fg];
      #pragma unroll
      for (int n5 = 0; n5 < 5; n5++){
        float tvv = (k==0) ? tv[n5].x : (k==1) ? tv[n5].y : (k==2) ? tv[n5].z : tv[n5].w;
        acc[n5][0] += tvv*wv.x; acc[n5][1] += tvv*wv.y;
        acc[n5][2] += tvv*wv.z; acc[n5][3] += tvv*wv.w;
      }
    }
  }
  #pragma unroll
  for (int n5 = 0; n5 < 5; n5++){
    int i = i0 + nr + n5*8;
    float mi = m[b*NN + i];
    float4 o4;
    o4.x = fmaxf(acc[n5][0], 0.f)*mi;
    o4.y = fmaxf(acc[n5][1], 0.f)*mi;
    o4.z = fmaxf(acc[n5][2], 0.f)*mi;
    o4.w = fmaxf(acc[n5][3], 0.f)*mi;
    ((float4*)&Hout[((size_t)b*NN + i)*CC])[fg] = o4;
  }
}

// ---------------- pool scores y_i = (H_i . p) / |p| ----------------
__global__ void k_score(const float* __restrict__ H, const float* __restrict__ p,
                        const float* __restrict__ pn, float* __restrict__ y){
  int blk = blockIdx.x, lane = threadIdx.x;  // grid 32000, block = 64
  int r8 = blk & 7, t = blk >> 3;            // t 0..3999
  int b = r8 + 8*(t/1000), i = t % 1000;
  const float* hrow = H + ((size_t)b*NN + i)*CC;
  float s = hrow[lane]*p[lane] + hrow[lane+64]*p[lane+64];
  for (int off = 32; off > 0; off >>= 1) s += __shfl_down(s, off);
  if (lane == 0) y[b*NN + i] = s / pn[0];
}

// ---- fused top-k pool + degree: one block per batch (R2-verified phases) ----
__global__ void k_pd(const float* __restrict__ y,
                     const short* __restrict__ idx, const int* __restrict__ cnt,
                     float* __restrict__ m, float* __restrict__ gate,
                     const int* __restrict__ ncur_in, int* __restrict__ ncur_out,
                     float* __restrict__ D, float* __restrict__ dg){
  __shared__ float yk[NN];
  __shared__ float ml[NN];
  int b = blockIdx.x, tid = threadIdx.x;   // grid = BB, block = 1024
  // ---- phase B: masked sort key (invalid -> +inf), remember old mask ----
  float mold = 0.f;
  if (tid < NN){
    mold = m[b*NN + tid];
    yk[tid] = (mold > 0.f) ? y[b*NN + tid] : INFINITY;
  }
  __syncthreads();
  // ---- phase C: rank scan + keep decision (identical to k_pool) ----
  int n = ncur_in[b];
  int nr = (int)((float)n * RMC);          // exact JAX semantics (f32 mult, trunc)
  int i = tid;
  float myv = (i < NN) ? yk[i] : INFINITY;
  int cn = 0;
  const float4* yk4 = (const float4*)yk;   // broadcast reads: conflict-free
  #pragma unroll 5
  for (int q = 0; q < 250; q++){
    float4 v = yk4[q];
    int j0 = q*4;
    cn += (int)((v.x < myv) || (v.x == myv && j0     < i));
    cn += (int)((v.y < myv) || (v.y == myv && j0 + 1 < i));
    cn += (int)((v.z < myv) || (v.z == myv && j0 + 2 < i));
    cn += (int)((v.w < myv) || (v.w == myv && j0 + 3 < i));
  }
  float gv = 0.f;
  if (i < NN){
    bool keep = (cn >= nr) && (mold > 0.f);
    gv = keep ? tanhf(yk[i]) : 0.f;        // yk[i] == raw y when kept
    m[b*NN + i]    = keep ? 1.0f : 0.0f;
    gate[b*NN + i] = gv;
    ml[i]          = keep ? 1.0f : 0.0f;
  }
  if (tid == 0) ncur_out[b] = n - nr;
  __syncthreads();
  // ---- phase D: degree from new mask (identical to k_deg) ----
  if (tid < NN){
    const short* r = idx + ((size_t)b*NN + tid)*CAP;
    int ne = cnt[b*NN + tid];
    float s0=0.f, s1=0.f, s2=0.f, s3=0.f;
    int k = 0;
    for (; k+4 <= ne; k += 4){
      s0 += ml[r[k]]; s1 += ml[r[k+1]]; s2 += ml[r[k+2]]; s3 += ml[r[k+3]];
    }
    for (; k < ne; k++) s0 += ml[r[k]];
    float Dv = 1.0f / sqrtf(((s0+s1)+(s2+s3)) + 1.0f + 1e-5f);
    D[b*NN + tid]  = Dv;
    dg[b*NN + tid] = Dv * gv;
  }
}

// ---- fused global max pool + FC: one block per batch (R2-verified) ----
__global__ void k_mfc(const float* __restrict__ H, const float* __restrict__ m,
                      const float* __restrict__ Wfc, const float* __restrict__ bfc,
                      float* __restrict__ out){
  __shared__ float part[8][CC];
  __shared__ float g[FF];
  int b = blockIdx.x, tid = threadIdx.x;   // grid = BB, block = 1024
  int sx = tid >> 7, c = tid & 127;
  float mx = 0.f;
  int i0 = sx*125;
  for (int i = i0; i < i0+125; i++){
    if (m[b*NN + i] != 0.f)
      mx = fmaxf(mx, H[((size_t)b*NN + i)*CC + c]);
  }
  part[sx][c] = mx;
  __syncthreads();
  if (tid < FF){
    float v = 0.f;
    #pragma unroll
    for (int s = 0; s < 8; s++) v = fmaxf(v, part[s][tid]);
    g[tid] = v;
  }
  __syncthreads();
  if (tid < OO){
    float acc = bfc[tid];
    for (int c2 = 0; c2 < FF; c2++) acc += g[c2]*Wfc[tid*FF + c2];
    out[b*OO + tid] = acc;
  }
}

extern "C" void kernel_launch(void* const* d_in, const int* in_sizes, int n_in,
                              void* d_out, int out_size, void* d_ws, size_t ws_size,
                              hipStream_t stream) {
  const float* x    = (const float*)d_in[0];
  const float* A    = (const float*)d_in[1];
  const float* mask = (const float*)d_in[2];
  const int*   Nn   = (const int*)  d_in[3];
  const float* W0   = (const float*)d_in[4];
  const float* b0   = (const float*)d_in[5];
  const float* W1   = (const float*)d_in[6];
  const float* b1   = (const float*)d_in[7];
  const float* W2   = (const float*)d_in[8];
  const float* b2   = (const float*)d_in[9];
  const float* p0   = (const float*)d_in[10];
  const float* p1   = (const float*)d_in[11];
  const float* Wfc  = (const float*)d_in[12];
  const float* bfc  = (const float*)d_in[13];
  float* out = (float*)d_out;

  // workspace carve (~42 MB)
  char* w = (char*)d_ws;
  float* H   = (float*)w; w += (size_t)BB*NN*CC*4;      // 16.38 MB (ping)
  float* H2  = (float*)w; w += (size_t)BB*NN*CC*4;      // 16.38 MB (pong)
  short* idx = (short*)w; w += (size_t)BB*NN*CAP*2;     // 8.19 MB
  float* Wt  = (float*)w; w += (size_t)3*FF*CC*4;       // 192 KB
  float* part= (float*)w; w += (size_t)8*BB*CC*4;       // 131 KB (unused)
  int*   cnt = (int*)w;   w += (size_t)BB*NN*4;
  float* D   = (float*)w; w += (size_t)BB*NN*4;
  float* m   = (float*)w; w += (size_t)BB*NN*4;
  float* ysc = (float*)w; w += (size_t)BB*NN*4;
  float* gate= (float*)w; w += (size_t)BB*NN*4;
  float* dg  = (float*)w; w += (size_t)BB*NN*4;
  int*   ncur= (int*)w;   w += 3*BB*sizeof(int);        // ping-pong slots
  float* pn  = (float*)w; w += 64;
  (void)part;

  // CSR + all pre-work in one dispatch
  k_csr<<<32032, 64, 0, stream>>>(A, mask, Nn, p0, p1, W0, W1, W2,
                                  idx, cnt, D, dg, m, gate, ncur, pn, Wt);

  // ---- stage 1: x -> H ----
  k_agglin<<<800, 256, 0, stream>>>(idx, cnt, D, dg, m, gate, x,
                                    Wt + 0*FF*CC, b0, H);
  k_score<<<32000, 64, 0, stream>>>(H, p0, pn + 0, ysc);
  k_pd<<<BB, 1024, 0, stream>>>(ysc, idx, cnt, m, gate,
                                ncur + 0*BB, ncur + 1*BB, D, dg);

  // ---- stage 2: H -> H2 ----
  k_agglin<<<800, 256, 0, stream>>>(idx, cnt, D, dg, m, gate, H,
                                    Wt + 1*FF*CC, b1, H2);
  k_score<<<32000, 64, 0, stream>>>(H2, p1, pn + 1, ysc);
  k_pd<<<BB, 1024, 0, stream>>>(ysc, idx, cnt, m, gate,
                                ncur + 1*BB, ncur + 2*BB, D, dg);

  // ---- stage 3: H2 -> H ----
  k_agglin<<<800, 256, 0, stream>>>(idx, cnt, D, dg, m, gate, H2,
                                    Wt + 2*FF*CC, b2, H);

  // ---- global max pool + FC (fused) ----
  k_mfc<<<BB, 1024, 0, stream>>>(H, m, Wfc, bfc, out);
}

// Round 7
// 443.062 us; speedup vs baseline: 1.1206x; 1.1206x over previous
//
#include <hip/hip_runtime.h>
#include <math.h>

#define BB 32
#define NN 1000
#define CC 128
#define FF 128
#define OO 64
#define CAP 128
#define NB 40

// exact replica of JAX's np.float32(1.0 - 0.8) = 0.20000000298023224f
#define RMC ((float)(1.0 - 0.8))

// ======== R17: agglin 256 -> 512 THREADS (8 waves, 5 rows/wave) ========
// R16 lesson (3rd confirmation): 32-block fusions lose ~25us each to starved
// parallelism vs ~12us boundary savings -> pd/mfc reverted to R5 split form.
// R5 model: agglin ~75us x3 dominated by phase-1 (12.5 waves/CU, 10 serial
// latency-chain rows per wave). This round: ONE variable - double phase-1
// wave parallelism (8 waves/block, 5 rows each). Row arithmetic untouched
// => bit-exact. Phase-2 = frozen GEMM verbatim under if(tid<256).

// ---- CSR build + stage-1 D/dg + fused pre-work (blocks with i==NN) ----
__global__ void k_csr(const float* __restrict__ A, const float* __restrict__ mask,
                      const int* __restrict__ Nn,
                      const float* __restrict__ p0, const float* __restrict__ p1,
                      const float* __restrict__ W0, const float* __restrict__ W1,
                      const float* __restrict__ W2,
                      short* __restrict__ idx, int* __restrict__ cnt,
                      float* __restrict__ D, float* __restrict__ dg,
                      float* __restrict__ m, float* __restrict__ gate,
                      int* __restrict__ ncur0, float* __restrict__ pn,
                      float* __restrict__ Wt){
  int blk = blockIdx.x, lane = threadIdx.x;   // grid 32032, block = 64 (one wave)
  int r8 = blk & 7, t = blk >> 3;             // t 0..4003
  int b = r8 + 8*(t/1001), i = t % 1001;      // XCD-spread decode
  if (i == NN){                            // ---- 32 pre-work blocks ----
    for (int j = lane; j < NN; j += 64){
      float v = mask[b*NN + j]; m[b*NN + j] = v; gate[b*NN + j] = v;
    }
    if (lane == 0) ncur0[b] = Nn[b];
    if (b == 0 && lane == 1){ float s=0.f; for(int c=0;c<FF;c++) s += p0[c]*p0[c]; pn[0] = sqrtf(s); }
    if (b == 1 && lane == 1){ float s=0.f; for(int c=0;c<FF;c++) s += p1[c]*p1[c]; pn[1] = sqrtf(s); }
    // Wt[s][c][f] = W[s][f][c]; 3*FF*CC = 49152 elems, 1536 per block
    for (int e = b*1536 + lane; e < (b+1)*1536; e += 64){
      int s = e / (FF*CC), rem = e % (FF*CC);
      int c = rem >> 7, f = rem & 127;
      const float* W = (s == 0) ? W0 : (s == 1) ? W1 : W2;
      Wt[(size_t)s*FF*CC + rem] = W[f*CC + c];
    }
    return;
  }
  if (mask[b*NN + i] == 0.f){              // A row is all-zero (A pre-masked)
    if (lane == 0){
      cnt[b*NN + i] = 0;
      D[b*NN + i]  = 1.0f / sqrtf(1.0f + 1e-5f);
      dg[b*NN + i] = 0.f;
    }
    return;
  }
  const float4* row = (const float4*)(A + ((size_t)b*NN + i)*NN);
  short* out = idx + ((size_t)b*NN + i)*CAP;
  int count = 0;
  for (int base = 0; base < 250; base += 64){               // 1000 = 250 float4
    int q = base + lane;
    float4 v;
    if (q < 250) v = row[q]; else { v.x=v.y=v.z=v.w=0.f; }
    int lc = (v.x!=0.f) + (v.y!=0.f) + (v.z!=0.f) + (v.w!=0.f);
    int pre = lc;
    #pragma unroll
    for (int off = 1; off < 64; off <<= 1){
      int t2 = __shfl_up(pre, off);
      if (lane >= off) pre += t2;
    }
    int tot = __shfl(pre, 63);
    pre -= lc;                                              // exclusive prefix
    int slot = count + pre;
    int j = q*4;
    if (v.x!=0.f && slot < CAP) out[slot++] = (short)j;
    if (v.y!=0.f && slot < CAP) out[slot++] = (short)(j+1);
    if (v.z!=0.f && slot < CAP) out[slot++] = (short)(j+2);
    if (v.w!=0.f && slot < CAP) out[slot++] = (short)(j+3);
    count += tot;
  }
  if (lane == 0){
    int cn = (count < CAP) ? count : CAP;
    cnt[b*NN + i] = cn;
    float Dv = 1.0f / sqrtf((float)cn + 1.0f + 1e-5f);
    D[b*NN + i]  = Dv;
    dg[b*NN + i] = Dv;                   // mask_i == 1 here
  }
}

// ---- FUSED: T-tile into LDS (phase 1, 8 waves x 5 rows) + frozen GEMM ----
// Spill tripwire: this kernel in top-5 with WRITE_SIZE >> 16MB => revert 512.
__global__ void k_agglin(const short* __restrict__ idx, const int* __restrict__ cnt,
                         const float* __restrict__ D, const float* __restrict__ dg,
                         const float* __restrict__ m, const float* __restrict__ gate,
                         const float* __restrict__ h,
                         const float* __restrict__ Wt,   // [cc][f] transposed
                         const float* __restrict__ bias, float* __restrict__ Hout){
  __shared__ float t[NB][CC];              // 20.5 KB (the old T staging buffer)
  __shared__ int   nb[8][CAP];             // per-wave gather scratch (4 KB)
  __shared__ float dn[8][CAP];             // (4 KB)
  int blk = blockIdx.x, tid = threadIdx.x; // grid 800, block = 512 (8 waves)
  int r8 = blk & 7, tq = blk >> 3;         // tq 0..99
  int b = r8 + 8*(tq/25);
  int i0 = (tq % 25) * NB;
  int w = tid >> 6, lane = tid & 63;
  int g = lane >> 5, l32 = lane & 31;
  const float* hb = h + (size_t)b*NN*CC;
  int*   nbw = nb[w];
  float* dnw = dn[w];
  // ================= phase 1: aggregate 40 rows into t (R5 body, 5 rows/wave) ====
  for (int q = 0; q < 5; q++){             // wave w owns local rows w, w+8, ... w+32
    int lr = q*8 + w;
    int i  = i0 + lr;
    if (m[b*NN + i] == 0.f){               // masked target: T row is zero
      if (g == 0){ float4 z = {0.f,0.f,0.f,0.f}; *(float4*)&t[lr][l32<<2] = z; }
      continue;                            // wave-uniform
    }
    int n = cnt[b*NN + i];
    const short* r = idx + ((size_t)b*NN + i)*CAP;
    // --- wave-level order-preserving compaction: keep edges with dn != 0 ---
    int j0 = 0; float d0 = 0.f; bool k0 = false;
    if (lane < n){ j0 = (int)r[lane]; d0 = dg[b*NN + j0]; k0 = (d0 != 0.f); }
    unsigned long long bal = __ballot(k0);
    int pre = __popcll(bal & ((1ull << lane) - 1ull));
    if (k0){ nbw[pre] = j0*CC; dnw[pre] = d0; }
    int nlive = __popcll(bal);
    if (n > 64){                           // wave-uniform branch
      int e = lane + 64; int j1 = 0; float d1 = 0.f; bool k1 = false;
      if (e < n){ j1 = (int)r[e]; d1 = dg[b*NN + j1]; k1 = (d1 != 0.f); }
      unsigned long long bal1 = __ballot(k1);
      int pre1 = __popcll(bal1 & ((1ull << lane) - 1ull));
      if (k1){ nbw[nlive + pre1] = j1*CC; dnw[nlive + pre1] = d1; }
      nlive += __popcll(bal1);
    }
    int np = (nlive + 15) & ~15;           // pad to 16 (CAP=128 safe)
    if (lane < np - nlive){ nbw[nlive + lane] = 0; dnw[nlive + lane] = 0.f; }
    __builtin_amdgcn_wave_barrier();       // fence: LDS writes before reads
    // --- branch-free float4 gather, 8 loads/lane in flight (R5 order) ---
    float4 a0 = {0.f,0.f,0.f,0.f}, a1 = a0, a2 = a0, a3 = a0;
    for (int k = 0; k < np; k += 16){
      int e = k + g;
      float4 v0 = *(const float4*)(hb + nbw[e   ] + (l32<<2));
      float4 v1 = *(const float4*)(hb + nbw[e+ 2] + (l32<<2));
      float4 v2 = *(const float4*)(hb + nbw[e+ 4] + (l32<<2));
      float4 v3 = *(const float4*)(hb + nbw[e+ 6] + (l32<<2));
      float4 v4 = *(const float4*)(hb + nbw[e+ 8] + (l32<<2));
      float4 v5 = *(const float4*)(hb + nbw[e+10] + (l32<<2));
      float4 v6 = *(const float4*)(hb + nbw[e+12] + (l32<<2));
      float4 v7 = *(const float4*)(hb + nbw[e+14] + (l32<<2));
      float e0 = dnw[e], e1 = dnw[e+2], e2 = dnw[e+4], e3 = dnw[e+6];
      float e4 = dnw[e+8], e5 = dnw[e+10], e6 = dnw[e+12], e7 = dnw[e+14];
      a0.x += e0*v0.x; a0.y += e0*v0.y; a0.z += e0*v0.z; a0.w += e0*v0.w;
      a1.x += e1*v1.x; a1.y += e1*v1.y; a1.z += e1*v1.z; a1.w += e1*v1.w;
      a2.x += e2*v2.x; a2.y += e2*v2.y; a2.z += e2*v2.z; a2.w += e2*v2.w;
      a3.x += e3*v3.x; a3.y += e3*v3.y; a3.z += e3*v3.z; a3.w += e3*v3.w;
      a0.x += e4*v4.x; a0.y += e4*v4.y; a0.z += e4*v4.z; a0.w += e4*v4.w;
      a1.x += e5*v5.x; a1.y += e5*v5.y; a1.z += e5*v5.z; a1.w += e5*v5.w;
      a2.x += e6*v6.x; a2.y += e6*v6.y; a2.z += e6*v6.z; a2.w += e6*v6.w;
      a3.x += e7*v7.x; a3.y += e7*v7.y; a3.z += e7*v7.z; a3.w += e7*v7.w;
    }
    float4 Y;
    Y.x = (a0.x + a1.x) + (a2.x + a3.x);
    Y.y = (a0.y + a1.y) + (a2.y + a3.y);
    Y.z = (a0.z + a1.z) + (a2.z + a3.z);
    Y.w = (a0.w + a1.w) + (a2.w + a3.w);
    Y.x += __shfl_xor(Y.x, 32);            // combine the two 32-lane groups
    Y.y += __shfl_xor(Y.y, 32);
    Y.z += __shfl_xor(Y.z, 32);
    Y.w += __shfl_xor(Y.w, 32);
    float Di = D[b*NN + i];
    float gi = gate[b*NN + i];
    if (g == 0){
      float4 hv = *(const float4*)(hb + (size_t)i*CC + (l32<<2));
      float4 o;
      o.x = Di*Y.x + Di*Di*(gi*hv.x);
      o.y = Di*Y.y + Di*Di*(gi*hv.y);
      o.z = Di*Y.z + Di*Di*(gi*hv.z);
      o.w = Di*Y.w + Di*Di*(gi*hv.w);
      *(float4*)&t[lr][l32<<2] = o;
    }
  }
  __syncthreads();
  // ================= phase 2: FROZEN R3 GEMM body (verbatim, waves 0-3) =====
  if (tid < 256){
    int fg = tid & 31;                     // 4 consecutive f per thread
    int nr = tid >> 5;                     // 0..7 node-row
    float acc[5][4];
    float4 bi = ((const float4*)bias)[fg];
    #pragma unroll
    for (int n5 = 0; n5 < 5; n5++){
      acc[n5][0]=bi.x; acc[n5][1]=bi.y; acc[n5][2]=bi.z; acc[n5][3]=bi.w;
    }
    for (int c4 = 0; c4 < 32; c4++){
      float4 tv[5];
      #pragma unroll
      for (int n5 = 0; n5 < 5; n5++)
        tv[n5] = *((const float4*)&t[nr + n5*8][c4*4]);
      #pragma unroll
      for (int k = 0; k < 4; k++){
        float4 wv = ((const float4*)Wt)[(size_t)(c4*4 + k)*32 + fg];
        #pragma unroll
        for (int n5 = 0; n5 < 5; n5++){
          float tvv = (k==0) ? tv[n5].x : (k==1) ? tv[n5].y : (k==2) ? tv[n5].z : tv[n5].w;
          acc[n5][0] += tvv*wv.x; acc[n5][1] += tvv*wv.y;
          acc[n5][2] += tvv*wv.z; acc[n5][3] += tvv*wv.w;
        }
      }
    }
    #pragma unroll
    for (int n5 = 0; n5 < 5; n5++){
      int i = i0 + nr + n5*8;
      float mi = m[b*NN + i];
      float4 o4;
      o4.x = fmaxf(acc[n5][0], 0.f)*mi;
      o4.y = fmaxf(acc[n5][1], 0.f)*mi;
      o4.z = fmaxf(acc[n5][2], 0.f)*mi;
      o4.w = fmaxf(acc[n5][3], 0.f)*mi;
      ((float4*)&Hout[((size_t)b*NN + i)*CC])[fg] = o4;
    }
  }
}

// ---------------- pool scores y_i = (H_i . p) / |p| ----------------
__global__ void k_score(const float* __restrict__ H, const float* __restrict__ p,
                        const float* __restrict__ pn, float* __restrict__ y){
  int blk = blockIdx.x, lane = threadIdx.x;  // grid 32000, block = 64
  int r8 = blk & 7, t = blk >> 3;            // t 0..3999
  int b = r8 + 8*(t/1000), i = t % 1000;
  const float* hrow = H + ((size_t)b*NN + i)*CC;
  float s = hrow[lane]*p[lane] + hrow[lane+64]*p[lane+64];
  for (int off = 32; off > 0; off >>= 1) s += __shfl_down(s, off);
  if (lane == 0) y[b*NN + i] = s / pn[0];
}

// ---------------- top-k pool: 1 node/thread, float4 LDS scan, ping-pong ncur ----------------
__global__ void k_pool(const float* __restrict__ y, float* __restrict__ m,
                       const int* __restrict__ ncur_in, int* __restrict__ ncur_out,
                       float* __restrict__ gate){
  __shared__ float yk[NN];
  int blk = blockIdx.x, tid = threadIdx.x;   // grid 128, block = 256
  int r8 = blk & 7, t = blk >> 3;            // t 0..15
  int b = r8 + 8*(t >> 2), xx = t & 3;
  int i = xx*256 + tid;
  for (int j = tid; j < NN; j += 256)
    yk[j] = (m[b*NN + j] > 0.f) ? y[b*NN + j] : INFINITY;
  __syncthreads();
  int n = ncur_in[b];
  int nr = (int)((float)n * RMC);          // exact JAX semantics (f32 mult, trunc)
  float myv = (i < NN) ? yk[i] : INFINITY;
  int cnt = 0;
  const float4* yk4 = (const float4*)yk;   // broadcast reads: conflict-free
  #pragma unroll 5
  for (int q = 0; q < 250; q++){
    float4 v = yk4[q];
    int j0 = q*4;
    cnt += (int)((v.x < myv) || (v.x == myv && j0     < i));
    cnt += (int)((v.y < myv) || (v.y == myv && j0 + 1 < i));
    cnt += (int)((v.z < myv) || (v.z == myv && j0 + 2 < i));
    cnt += (int)((v.w < myv) || (v.w == myv && j0 + 3 < i));
  }
  if (i < NN){
    bool keep = (cnt >= nr) && (m[b*NN + i] > 0.f);
    m[b*NN + i]    = keep ? 1.0f : 0.0f;
    gate[b*NN + i] = keep ? tanhf(y[b*NN + i]) : 0.0f;
  }
  if (xx == 0 && tid == 0) ncur_out[b] = n - nr;
}

// ---------------- degree from new mask -> D, dg = D*gate ----------------
__global__ void k_deg(const short* __restrict__ idx, const int* __restrict__ cnt,
                      const float* __restrict__ m, const float* __restrict__ gate,
                      float* __restrict__ D, float* __restrict__ dg){
  __shared__ float ml[NN];
  int blk = blockIdx.x, tid = threadIdx.x;   // grid 128, block = 256
  int r8 = blk & 7, t = blk >> 3;            // t 0..15
  int b = r8 + 8*(t >> 2), xx = t & 3;
  for (int i = tid; i < NN; i += 256) ml[i] = m[b*NN + i];
  __syncthreads();
  int j = xx*250 + tid;
  if (tid < 250){
    const short* r = idx + ((size_t)b*NN + j)*CAP;
    int n = cnt[b*NN + j];
    float s0=0.f, s1=0.f, s2=0.f, s3=0.f;
    int k = 0;
    for (; k+4 <= n; k += 4){
      s0 += ml[r[k]]; s1 += ml[r[k+1]]; s2 += ml[r[k+2]]; s3 += ml[r[k+3]];
    }
    for (; k < n; k++) s0 += ml[r[k]];
    float Dv = 1.0f / sqrtf(((s0+s1)+(s2+s3)) + 1.0f + 1e-5f);
    D[b*NN + j]  = Dv;
    dg[b*NN + j] = Dv * gate[b*NN + j];
  }
}

// ---------------- partial global max pool (masked rows skipped; relu => max>=0) ----------------
__global__ void k_fmax(const float* __restrict__ H, const float* __restrict__ m,
                       float* __restrict__ part){
  int blk = blockIdx.x, c = threadIdx.x;     // grid 256, block = 128
  int r8 = blk & 7, t = blk >> 3;            // t 0..31
  int b = r8 + 8*(t >> 3), sx = t & 7;
  float mx = 0.f;
  int i0 = sx*125;
  for (int i = i0; i < i0+125; i++){
    if (m[b*NN + i] != 0.f)
      mx = fmaxf(mx, H[((size_t)b*NN + i)*CC + c]);
  }
  part[((size_t)b*8 + sx)*CC + c] = mx;
}

// ---------------- combine partial maxima + FC ----------------
__global__ void k_fc(const float* __restrict__ part, const float* __restrict__ Wfc,
                     const float* __restrict__ bfc, float* __restrict__ out){
  __shared__ float g[FF];
  int b = blockIdx.x, tid = threadIdx.x;   // block = 128
  float mx = 0.f;
  #pragma unroll
  for (int s = 0; s < 8; s++) mx = fmaxf(mx, part[((size_t)b*8 + s)*CC + tid]);
  g[tid] = mx;
  __syncthreads();
  if (tid < OO){
    float acc = bfc[tid];
    for (int c = 0; c < FF; c++) acc += g[c]*Wfc[tid*FF + c];
    out[b*OO + tid] = acc;
  }
}

extern "C" void kernel_launch(void* const* d_in, const int* in_sizes, int n_in,
                              void* d_out, int out_size, void* d_ws, size_t ws_size,
                              hipStream_t stream) {
  const float* x    = (const float*)d_in[0];
  const float* A    = (const float*)d_in[1];
  const float* mask = (const float*)d_in[2];
  const int*   Nn   = (const int*)  d_in[3];
  const float* W0   = (const float*)d_in[4];
  const float* b0   = (const float*)d_in[5];
  const float* W1   = (const float*)d_in[6];
  const float* b1   = (const float*)d_in[7];
  const float* W2   = (const float*)d_in[8];
  const float* b2   = (const float*)d_in[9];
  const float* p0   = (const float*)d_in[10];
  const float* p1   = (const float*)d_in[11];
  const float* Wfc  = (const float*)d_in[12];
  const float* bfc  = (const float*)d_in[13];
  float* out = (float*)d_out;

  // workspace carve (~42 MB)
  char* w = (char*)d_ws;
  float* H   = (float*)w; w += (size_t)BB*NN*CC*4;      // 16.38 MB (ping)
  float* H2  = (float*)w; w += (size_t)BB*NN*CC*4;      // 16.38 MB (pong)
  short* idx = (short*)w; w += (size_t)BB*NN*CAP*2;     // 8.19 MB
  float* Wt  = (float*)w; w += (size_t)3*FF*CC*4;       // 192 KB
  float* part= (float*)w; w += (size_t)8*BB*CC*4;       // 131 KB
  int*   cnt = (int*)w;   w += (size_t)BB*NN*4;
  float* D   = (float*)w; w += (size_t)BB*NN*4;
  float* m   = (float*)w; w += (size_t)BB*NN*4;
  float* ysc = (float*)w; w += (size_t)BB*NN*4;
  float* gate= (float*)w; w += (size_t)BB*NN*4;
  float* dg  = (float*)w; w += (size_t)BB*NN*4;
  int*   ncur= (int*)w;   w += 3*BB*sizeof(int);        // ping-pong slots
  float* pn  = (float*)w; w += 64;

  // CSR + all pre-work in one dispatch
  k_csr<<<32032, 64, 0, stream>>>(A, mask, Nn, p0, p1, W0, W1, W2,
                                  idx, cnt, D, dg, m, gate, ncur, pn, Wt);

  // ---- stage 1: x -> H ----
  k_agglin<<<800, 512, 0, stream>>>(idx, cnt, D, dg, m, gate, x,
                                    Wt + 0*FF*CC, b0, H);
  k_score<<<32000, 64, 0, stream>>>(H, p0, pn + 0, ysc);
  k_pool<<<128, 256, 0, stream>>>(ysc, m, ncur + 0*BB, ncur + 1*BB, gate);
  k_deg<<<128, 256, 0, stream>>>(idx, cnt, m, gate, D, dg);

  // ---- stage 2: H -> H2 ----
  k_agglin<<<800, 512, 0, stream>>>(idx, cnt, D, dg, m, gate, H,
                                    Wt + 1*FF*CC, b1, H2);
  k_score<<<32000, 64, 0, stream>>>(H2, p1, pn + 1, ysc);
  k_pool<<<128, 256, 0, stream>>>(ysc, m, ncur + 1*BB, ncur + 2*BB, gate);
  k_deg<<<128, 256, 0, stream>>>(idx, cnt, m, gate, D, dg);

  // ---- stage 3: H2 -> H ----
  k_agglin<<<800, 512, 0, stream>>>(idx, cnt, D, dg, m, gate, H2,
                                    Wt + 2*FF*CC, b2, H);

  // ---- global max pool + FC ----
  k_fmax<<<256, 128, 0, stream>>>(H, m, part);
  k_fc<<<BB, 128, 0, stream>>>(part, Wfc, bfc, out);
}